// Round 1
// baseline (1270.335 us; speedup 1.0000x reference)
//
#include <hip/hip_runtime.h>
#include <math.h>

#define C 64
#define NHEADS 4
#define DH 16
#define NN 262144   // H*W
#define NB 2
#define NCOPY 8
#define EPS 1e-12f

// ---------------- K1: per-batch Gram matrix G = X X^T (64x64) ----------------
// grid 1024 (512 blocks/batch), 256 threads. Block covers 512 cols = 4 tiles x 128.
// LDS tile layout: row c (128 floats), quad j>>2 stored at (q ^ ((c>>3)&7)) -> all
// b128 LDS reads/writes bank-conflict-free.
__global__ __launch_bounds__(256, 2) void gram_kernel(const float* __restrict__ x,
                                                      float* __restrict__ Gc) {
  __shared__ float lds[C * 128];
  const int blk = blockIdx.x;
  const int b = blk >> 9;
  const int chunk = blk & 511;
  const float* xb = x + (size_t)b * C * NN;
  const int t = threadIdx.x;
  const int wid = t >> 6;
  const int lane = t & 63;
  const int ly = lane >> 3, lx = lane & 7;

  float acc[8][8];
#pragma unroll
  for (int a = 0; a < 8; ++a)
#pragma unroll
    for (int bb = 0; bb < 8; ++bb) acc[a][bb] = 0.f;

  for (int tile = 0; tile < 4; ++tile) {
    const int j0 = chunk * 512 + tile * 128;
    __syncthreads();
#pragma unroll
    for (int i = 0; i < 8; ++i) {
      const int idx = i * 256 + t;
      const int c = idx >> 5, jq = idx & 31;
      const float4 v = *reinterpret_cast<const float4*>(xb + (size_t)c * NN + j0 + jq * 4);
      const int sq = jq ^ ((c >> 3) & 7);
      *reinterpret_cast<float4*>(&lds[c * 128 + sq * 4]) = v;
    }
    __syncthreads();
    // wave wid handles quads [8*wid, 8*wid+8)
#pragma unroll
    for (int qi = 0; qi < 8; ++qi) {
      const int q = wid * 8 + qi;
      float4 f1[8], f2[8];
#pragma unroll
      for (int a = 0; a < 8; ++a) {
        const int c1 = ly * 8 + a;
        f1[a] = *reinterpret_cast<const float4*>(&lds[c1 * 128 + ((q ^ ly) << 2)]);
        const int c2 = lx * 8 + a;
        f2[a] = *reinterpret_cast<const float4*>(&lds[c2 * 128 + ((q ^ lx) << 2)]);
      }
#pragma unroll
      for (int a = 0; a < 8; ++a)
#pragma unroll
        for (int bb = 0; bb < 8; ++bb)
          acc[a][bb] += f1[a].x * f2[bb].x + f1[a].y * f2[bb].y +
                        f1[a].z * f2[bb].z + f1[a].w * f2[bb].w;
    }
  }
  // cross-wave reduce into lds[0..4096)
  __syncthreads();
  for (int w = 0; w < 4; ++w) {
    if (wid == w) {
#pragma unroll
      for (int a = 0; a < 8; ++a)
#pragma unroll
        for (int bb = 0; bb < 8; ++bb) {
          const int r = ly * 8 + a, cg = lx * 8 + bb;
          if (w == 0) lds[r * 64 + cg] = acc[a][bb];
          else        lds[r * 64 + cg] += acc[a][bb];
        }
    }
    __syncthreads();
  }
  float* g = Gc + ((size_t)b * NCOPY + (chunk & (NCOPY - 1))) * 4096;
  for (int i = t; i < 4096; i += 256) atomicAdd(&g[i], lds[i]);
}

// ---------------- K2: all attention math on 64x64 matrices ----------------
// grid 2 (one block per batch). Produces E[b] = Wp * BD(softmax(attn)) * Wv + I.
__global__ __launch_bounds__(256) void attn_kernel(const float* __restrict__ Gc,
    const float* __restrict__ Wq, const float* __restrict__ Wk,
    const float* __restrict__ Wv, const float* __restrict__ Wp,
    const float* __restrict__ rescale, float* __restrict__ E) {
  __shared__ float Gs[4096], GQt[4096], GKt[4096], T[4096];
  __shared__ float attnw[64][DH];
  __shared__ float nq[64], nk[64];
  const int b = blockIdx.x;
  const int t = threadIdx.x;

  // reduce the NCOPY partial Grams
  for (int i = t; i < 4096; i += 256) {
    float s = 0.f;
    for (int cp = 0; cp < NCOPY; ++cp) s += Gc[((size_t)b * NCOPY + cp) * 4096 + i];
    Gs[i] = s;
  }
  __syncthreads();
  // GQt[c][e] = (G Wq^T)[c][e],  GKt[c][e] = (G Wk^T)[c][e]
  for (int i = t; i < 4096; i += 256) {
    const int c = i >> 6, e = i & 63;
    float sq_ = 0.f, sk_ = 0.f;
    for (int c2 = 0; c2 < 64; ++c2) {
      const float g = Gs[c * 64 + c2];
      sq_ += g * Wq[e * 64 + c2];
      sk_ += g * Wk[e * 64 + c2];
    }
    GQt[c * 64 + e] = sq_;
    GKt[c * 64 + e] = sk_;
  }
  __syncthreads();
  if (t < 64) {
    float s = 0.f;
    for (int c2 = 0; c2 < 64; ++c2) s += Wq[t * 64 + c2] * GQt[c2 * 64 + t];
    nq[t] = sqrtf(fmaxf(s, 0.f));
  } else if (t < 128) {
    const int d = t - 64;
    float s = 0.f;
    for (int c2 = 0; c2 < 64; ++c2) s += Wk[d * 64 + c2] * GKt[c2 * 64 + d];
    nk[d] = sqrtf(fmaxf(s, 0.f));
  }
  __syncthreads();
  // per attention row (64 rows): logits -> softmax
  if (t < 64) {
    const int h = t >> 4;
    const float rs = rescale[h];
    const float nkd = fmaxf(nk[t], EPS);
    float logits[DH];
    float mx = -1e30f;
    for (int ee = 0; ee < DH; ++ee) {
      const int e = h * DH + ee;
      float num = 0.f;
      for (int c2 = 0; c2 < 64; ++c2) num += Wk[t * 64 + c2] * GQt[c2 * 64 + e];
      const float l = num / (nkd * fmaxf(nq[e], EPS)) * rs;
      logits[ee] = l;
      mx = fmaxf(mx, l);
    }
    float sum = 0.f;
    for (int ee = 0; ee < DH; ++ee) { const float p = expf(logits[ee] - mx); logits[ee] = p; sum += p; }
    const float inv = 1.f / sum;
    for (int ee = 0; ee < DH; ++ee) attnw[t][ee] = logits[ee] * inv;
  }
  __syncthreads();
  // T = BD(attn) * Wv
  for (int i = t; i < 4096; i += 256) {
    const int r = i >> 6, c = i & 63;
    const int h = r >> 4;
    float s = 0.f;
    for (int e = 0; e < DH; ++e) s += attnw[r][e] * Wv[(h * DH + e) * 64 + c];
    T[i] = s;
  }
  __syncthreads();
  // E = Wp * T + I
  for (int i = t; i < 4096; i += 256) {
    const int r = i >> 6, c = i & 63;
    float s = (r == c) ? 1.f : 0.f;
    for (int m = 0; m < 64; ++m) s += Wp[r * 64 + m] * T[m * 64 + c];
    E[(size_t)b * 4096 + i] = s;
  }
}

// ---------------- K3: out = (E+I) * x + bp ----------------
// grid 1024 (512/batch), 256 threads, 4 tiles x 128 cols per block.
__global__ __launch_bounds__(256, 2) void apply_kernel(const float* __restrict__ x,
    const float* __restrict__ E, const float* __restrict__ bp,
    float* __restrict__ out) {
  __shared__ float xt[C * 128];
  __shared__ float Mt[C * 68];   // Mt[k][c] = M[c][k], stride 68
  const int blk = blockIdx.x;
  const int b = blk >> 9;
  const int chunk = blk & 511;
  const float* xb = x + (size_t)b * C * NN;
  float* ob = out + (size_t)b * C * NN;
  const int t = threadIdx.x;
  const int wid = t >> 6, lane = t & 63;
  const int ly = lane >> 3, lx = lane & 7;

  for (int i = t; i < 4096; i += 256) {
    const int k = i >> 6, c = i & 63;
    Mt[k * 68 + c] = E[(size_t)b * 4096 + c * 64 + k];
  }

  for (int tile = 0; tile < 4; ++tile) {
    const int j0 = chunk * 512 + tile * 128;
    __syncthreads();
#pragma unroll
    for (int i = 0; i < 8; ++i) {
      const int idx = i * 256 + t;
      const int c = idx >> 5, jq = idx & 31;
      const float4 v = *reinterpret_cast<const float4*>(xb + (size_t)c * NN + j0 + jq * 4);
      const int sq = jq ^ ((c >> 3) & 7);
      *reinterpret_cast<float4*>(&xt[c * 128 + sq * 4]) = v;
    }
    __syncthreads();
    const int qL = wid * 8 + lx;  // this lane's quad within the 128-col tile
    float acc[8][4];
#pragma unroll
    for (int a = 0; a < 8; ++a)
#pragma unroll
      for (int r = 0; r < 4; ++r) acc[a][r] = 0.f;
#pragma unroll 4
    for (int k = 0; k < 64; ++k) {
      const float4 m0 = *reinterpret_cast<const float4*>(&Mt[k * 68 + ly * 8]);
      const float4 m1 = *reinterpret_cast<const float4*>(&Mt[k * 68 + ly * 8 + 4]);
      const float4 xv = *reinterpret_cast<const float4*>(&xt[k * 128 + ((qL ^ ((k >> 3) & 7)) << 2)]);
      const float mv[8] = {m0.x, m0.y, m0.z, m0.w, m1.x, m1.y, m1.z, m1.w};
#pragma unroll
      for (int a = 0; a < 8; ++a) {
        acc[a][0] += mv[a] * xv.x;
        acc[a][1] += mv[a] * xv.y;
        acc[a][2] += mv[a] * xv.z;
        acc[a][3] += mv[a] * xv.w;
      }
    }
#pragma unroll
    for (int a = 0; a < 8; ++a) {
      const int c1 = ly * 8 + a;
      const float bias = bp[c1];
      float4 o4;
      o4.x = acc[a][0] + bias;
      o4.y = acc[a][1] + bias;
      o4.z = acc[a][2] + bias;
      o4.w = acc[a][3] + bias;
      *reinterpret_cast<float4*>(&ob[(size_t)c1 * NN + j0 + qL * 4]) = o4;
    }
  }
}

extern "C" void kernel_launch(void* const* d_in, const int* in_sizes, int n_in,
                              void* d_out, int out_size, void* d_ws, size_t ws_size,
                              hipStream_t stream) {
  const float* x       = (const float*)d_in[0];
  const float* Wq      = (const float*)d_in[1];
  const float* Wk      = (const float*)d_in[2];
  const float* Wv      = (const float*)d_in[3];
  const float* Wp      = (const float*)d_in[4];
  const float* bp      = (const float*)d_in[5];
  const float* rescale = (const float*)d_in[6];
  float* out = (float*)d_out;

  float* Gc = (float*)d_ws;                                   // 2*NCOPY*4096 floats
  float* E  = (float*)((char*)d_ws + (size_t)NB * NCOPY * 4096 * sizeof(float));

  hipMemsetAsync(d_ws, 0, (size_t)NB * NCOPY * 4096 * sizeof(float), stream);
  gram_kernel<<<dim3(1024), dim3(256), 0, stream>>>(x, Gc);
  attn_kernel<<<dim3(NB), dim3(256), 0, stream>>>(Gc, Wq, Wk, Wv, Wp, rescale, E);
  apply_kernel<<<dim3(1024), dim3(256), 0, stream>>>(x, E, bp, out);
}